// Round 2
// baseline (4135.623 us; speedup 1.0000x reference)
//
#include <hip/hip_runtime.h>
#include <hip/hip_bf16.h>

typedef __hip_bfloat16 bf16;
typedef __attribute__((ext_vector_type(8))) short short8;
typedef __attribute__((ext_vector_type(4))) float f32x4;

#define NN 100000
#define NE 1600000

// ---------------- dtype detection ----------------
// If x is bf16: low 16 bits of each uint32 word are a bf16 with exponent
// (bits 14..7) in ~[100,141] for N(0,1) data -> nearly all 256 samples hit.
// If x is fp32: bits 14..7 are mantissa bits (uniform) -> ~16% hit.
__global__ void detect_kernel(const unsigned int* __restrict__ x, int* __restrict__ flags) {
    __shared__ int s;
    if (threadIdx.x == 0) s = 0;
    __syncthreads();
    int c = 0;
    for (int j = 0; j < 4; ++j) {
        unsigned int w = x[threadIdx.x * 4 + j];
        unsigned int e = (w >> 7) & 0xFF;
        if (e >= 100 && e <= 141) c++;
    }
    atomicAdd(&s, c);
    __syncthreads();
    if (threadIdx.x == 0) flags[0] = (s > 128) ? 1 : 0;
}

// ---------------- input canonicalization ----------------
// 4 elements/thread. bf16 source: plain 8-byte copy. fp32 source: convert.
__global__ __launch_bounds__(256) void cvt_bf16_kernel(const void* __restrict__ in,
                                                       bf16* __restrict__ out, int n4,
                                                       const int* __restrict__ flagp) {
    int i = blockIdx.x * 256 + threadIdx.x;
    if (i >= n4) return;
    if (flagp[0]) {
        ((uint2*)out)[i] = ((const uint2*)in)[i];
    } else {
        float4 f = ((const float4*)in)[i];
        size_t o = (size_t)i * 4;
        out[o + 0] = __float2bfloat16(f.x);
        out[o + 1] = __float2bfloat16(f.y);
        out[o + 2] = __float2bfloat16(f.z);
        out[o + 3] = __float2bfloat16(f.w);
    }
}

__global__ __launch_bounds__(256) void cvt_f32_kernel(const void* __restrict__ in,
                                                      float* __restrict__ out, int n,
                                                      const int* __restrict__ flagp) {
    int i = blockIdx.x * 256 + threadIdx.x;
    if (i >= n) return;
    if (flagp[0]) out[i] = __bfloat162float(((const bf16*)in)[i]);
    else out[i] = ((const float*)in)[i];
}

__global__ __launch_bounds__(256) void fill_kernel(bf16* __restrict__ out, long long n) {
    long long i = (long long)blockIdx.x * 256 + threadIdx.x;
    if (i < n) out[i] = __float2bfloat16(1000.0f);
}

// ---------------- CSR build ----------------

__global__ __launch_bounds__(256) void count_kernel(const int* __restrict__ dst,
                                                    int* __restrict__ cnt) {
    int e = blockIdx.x * 256 + threadIdx.x;
    if (e < NE) atomicAdd(&cnt[dst[e]], 1);
}

__global__ __launch_bounds__(1024) void scan_kernel(const int* __restrict__ cnt,
                                                    int* __restrict__ indptr,
                                                    int* __restrict__ cursor,
                                                    float* __restrict__ recip) {
    __shared__ int lds[1024];
    const int SEG = (NN + 1023) / 1024;  // 98
    int t = threadIdx.x;
    int base = t * SEG;
    int s = 0;
    for (int i = 0; i < SEG; ++i) {
        int idx = base + i;
        if (idx < NN) s += cnt[idx];
    }
    lds[t] = s;
    __syncthreads();
    for (int off = 1; off < 1024; off <<= 1) {
        int v = (t >= off) ? lds[t - off] : 0;
        __syncthreads();
        lds[t] += v;
        __syncthreads();
    }
    int run = lds[t] - s;  // exclusive prefix
    for (int i = 0; i < SEG; ++i) {
        int idx = base + i;
        if (idx < NN) {
            int c = cnt[idx];
            indptr[idx] = run;
            cursor[idx] = run;
            recip[idx] = 1.0f / (float)(c > 1 ? c : 1);
            run += c;
        }
    }
    if (t == 1023) indptr[NN] = lds[1023];
}

__global__ __launch_bounds__(256) void scatter_kernel(const int* __restrict__ src,
                                                      const int* __restrict__ dst,
                                                      int* __restrict__ cursor,
                                                      int* __restrict__ csr) {
    int e = blockIdx.x * 256 + threadIdx.x;
    if (e < NE) {
        int d = dst[e];
        int p = atomicAdd(&cursor[d], 1);
        csr[p] = src[e];
    }
}

// ---------------- aggregation (pull over CSR) ----------------
// ADD=0: out[node,c] = mean_j u[j,c]
// ADD=1: out[node,c] = bf16(float(out[node,c]) + mean_j u[j,c])
template <int ADD>
__global__ __launch_bounds__(256) void agg_kernel(const bf16* __restrict__ u,
                                                  const int* __restrict__ indptr,
                                                  const int* __restrict__ csr,
                                                  const float* __restrict__ recip,
                                                  int ld,  // log2(D)
                                                  bf16* __restrict__ out) {
    int node = blockIdx.x * (256 >> ld) + (threadIdx.x >> ld);
    int c = threadIdx.x & ((1 << ld) - 1);
    if (node >= NN) return;
    int j0 = indptr[node], j1 = indptr[node + 1];
    float acc = 0.f;
    for (int j = j0; j < j1; ++j) {
        int sIdx = csr[j];
        acc += __bfloat162float(u[((size_t)sIdx << ld) + c]);
    }
    float v = acc * recip[node];
    size_t o = ((size_t)node << ld) + c;
    if (ADD) v += __bfloat162float(out[o]);
    out[o] = __float2bfloat16(v);
}

// ---------------- bf16 MFMA GEMM:  out = A1@W1^T (+ A2@W2^T) (+ bias) ----------------
// A: M x K row-major bf16.  W: N x K row-major bf16 (i.e. B^T layout).
// 64x64 tile per 256-thread block; wave w owns rows [16w,16w+16) x 64 cols.
// If outFinal != nullptr this is the network output: write bf16 or fp32 per flag.
#define LDS_ROW_U 20  // 40 bf16 per LDS row (padded from 32 -> 2-way-max bank aliasing)

__global__ __launch_bounds__(256) void gemm_kernel(
    const bf16* __restrict__ A1, const bf16* __restrict__ W1, int K1,
    const bf16* __restrict__ A2, const bf16* __restrict__ W2, int K2,
    const float* __restrict__ bias,
    bf16* __restrict__ outB, void* __restrict__ outFinal,
    const int* __restrict__ flagp,
    int M, int N) {
    __shared__ unsigned int sA[64 * LDS_ROW_U];
    __shared__ unsigned int sW[64 * LDS_ROW_U];

    int tid = threadIdx.x;
    int lane = tid & 63, wv = tid >> 6;
    int lrow = lane & 15, lq = lane >> 4;
    int m0 = blockIdx.x * 64, n0 = blockIdx.y * 64;
    int isbf = flagp[0];

    f32x4 acc[4];
#pragma unroll
    for (int t = 0; t < 4; ++t) acc[t] = (f32x4){0.f, 0.f, 0.f, 0.f};

    int srow = tid >> 2;          // 0..63 staging row
    int skoff = (tid & 3) * 4;    // uint offset within 32-bf16 row chunk

#pragma unroll 1
    for (int seg = 0; seg < 2; ++seg) {
        const bf16* A = seg ? A2 : A1;
        const bf16* W = seg ? W2 : W1;
        int K = seg ? K2 : K1;
        if (K == 0) continue;
        const unsigned int* Au = (const unsigned int*)A;
        const unsigned int* Wu = (const unsigned int*)W;
        int Ku = K >> 1;  // uints per row (K always even here)

        for (int k0 = 0; k0 < K; k0 += 32) {
            __syncthreads();
            int kb = (k0 >> 1) + skoff;
            {   // stage A tile (64 rows x 32 bf16), zero-pad OOB
                int gm = m0 + srow;
                unsigned int v0 = 0, v1 = 0, v2 = 0, v3 = 0;
                if (gm < M) {
                    const unsigned int* p = Au + (size_t)gm * Ku + kb;
                    if (kb + 0 < Ku) v0 = p[0];
                    if (kb + 1 < Ku) v1 = p[1];
                    if (kb + 2 < Ku) v2 = p[2];
                    if (kb + 3 < Ku) v3 = p[3];
                }
                unsigned int* q = &sA[srow * LDS_ROW_U + skoff];
                q[0] = v0; q[1] = v1; q[2] = v2; q[3] = v3;
            }
            {   // stage W tile (64 rows x 32 bf16); N is always a multiple of 64
                int gn = n0 + srow;
                unsigned int v0 = 0, v1 = 0, v2 = 0, v3 = 0;
                const unsigned int* p = Wu + (size_t)gn * Ku + kb;
                if (kb + 0 < Ku) v0 = p[0];
                if (kb + 1 < Ku) v1 = p[1];
                if (kb + 2 < Ku) v2 = p[2];
                if (kb + 3 < Ku) v3 = p[3];
                unsigned int* q = &sW[srow * LDS_ROW_U + skoff];
                q[0] = v0; q[1] = v1; q[2] = v2; q[3] = v3;
            }
            __syncthreads();
            // A-frag: lane holds A[m=lane&15][k=quad*8+j] (8 bf16 = ds_read_b128)
            short8 a = *(const short8*)&sA[(wv * 16 + lrow) * LDS_ROW_U + lq * 4];
#pragma unroll
            for (int t = 0; t < 4; ++t) {
                short8 b = *(const short8*)&sW[(t * 16 + lrow) * LDS_ROW_U + lq * 4];
                acc[t] = __builtin_amdgcn_mfma_f32_16x16x32_bf16(a, b, acc[t], 0, 0, 0);
            }
        }
    }

    // epilogue: C/D layout col=lane&15, row=quad*4+reg
#pragma unroll
    for (int t = 0; t < 4; ++t) {
        int gcol = n0 + t * 16 + lrow;
        float bv = bias ? bias[gcol] : 0.f;
#pragma unroll
        for (int r = 0; r < 4; ++r) {
            int grow = m0 + wv * 16 + lq * 4 + r;
            if (grow < M) {
                size_t o = (size_t)grow * N + gcol;
                float v = acc[t][r] + bv;
                if (outFinal) {
                    if (isbf) ((bf16*)outFinal)[o] = __float2bfloat16(v);
                    else ((float*)outFinal)[o] = v;
                } else {
                    outB[o] = __float2bfloat16(v);
                }
            }
        }
    }
}

// ---------------- BatchNorm ----------------

__global__ __launch_bounds__(256) void bn_stats_kernel(const bf16* __restrict__ C,
                                                       int ldN,
                                                       float* __restrict__ stats) {
    int N = 1 << ldN;
    int tid = threadIdx.x;
    int c = tid & (N - 1);
    int rsub = tid >> ldN;
    int rstep = 256 >> ldN;
    int r0 = blockIdx.x * 64;
    float s = 0.f, q = 0.f;
    for (int r = r0 + rsub; r < r0 + 64; r += rstep) {
        if (r < NN) {
            float v = __bfloat162float(C[(size_t)r * N + c]);
            s += v;
            q += v * v;
        }
    }
    __shared__ float ls[256], lq[256];
    ls[tid] = s;
    lq[tid] = q;
    __syncthreads();
    for (int half = rstep >> 1; half > 0; half >>= 1) {
        if (rsub < half) {
            ls[tid] += ls[tid + half * N];
            lq[tid] += lq[tid + half * N];
        }
        __syncthreads();
    }
    if (rsub == 0) {
        atomicAdd(&stats[c], ls[tid]);
        atomicAdd(&stats[N + c], lq[tid]);
    }
}

__global__ __launch_bounds__(256) void bn_finalize_kernel(const float* __restrict__ stats,
                                                          const float* __restrict__ g,
                                                          const float* __restrict__ be,
                                                          int N,
                                                          float* __restrict__ scale,
                                                          float* __restrict__ shift) {
    int c = threadIdx.x;
    if (c >= N) return;
    float mean = stats[c] * (1.0f / NN);
    float var = stats[N + c] * (1.0f / NN) - mean * mean;
    var = fmaxf(var, 0.f);
    float sc = g[c] * rsqrtf(var + 1e-5f);
    scale[c] = sc;
    shift[c] = be[c] - mean * sc;
}

// in-place: act may equal C
__global__ __launch_bounds__(256) void bn_apply_kernel(const bf16* __restrict__ C,
                                                       const float* __restrict__ scale,
                                                       const float* __restrict__ shift,
                                                       int mask,  // N-1
                                                       bf16* __restrict__ act,
                                                       long long total) {
    long long i = (long long)blockIdx.x * 256 + threadIdx.x;
    if (i < total) {
        int c = (int)(i & mask);
        float v = __bfloat162float(C[i]) * scale[c] + shift[c];
        act[i] = __float2bfloat16(v > 0.f ? v : 0.f);
    }
}

// ---------------- host launch ----------------

extern "C" void kernel_launch(void* const* d_in, const int* in_sizes, int n_in,
                              void* d_out, int out_size, void* d_ws, size_t ws_size,
                              hipStream_t stream) {
    const void* x_raw = d_in[0];
    const int* ei = (const int*)d_in[1];
    const int* src = ei;
    const int* dst = ei + NE;

    // workspace layout (~164 MB)
    char* w = (char*)d_ws;
    size_t off = 0;
    auto alloc = [&](size_t bytes) {
        void* p = w + off;
        off = (off + bytes + 255) & ~(size_t)255;
        return p;
    };
    int* flags = (int*)alloc(256);
    int* cnt = (int*)alloc((size_t)NN * 4);
    int* indptr = (int*)alloc((size_t)(NN + 1) * 4);
    int* cursor = (int*)alloc((size_t)NN * 4);
    float* recip = (float*)alloc((size_t)NN * 4);
    int* csr = (int*)alloc((size_t)NE * 4);
    // canonical bf16 weights + fp32 bias/gamma/beta
    const int KDIM[5] = {196, 64, 128, 256, 256};
    const int NDIM[5] = {64, 128, 256, 256, 576};
    bf16 *Wlb[5], *Wrb[5];
    float *bf_[5], *gf[4], *bef[4];
    for (int i = 0; i < 5; ++i) {
        Wlb[i] = (bf16*)alloc((size_t)KDIM[i] * NDIM[i] * 2);
        Wrb[i] = (bf16*)alloc((size_t)KDIM[i] * NDIM[i] * 2);
        bf_[i] = (float*)alloc((size_t)NDIM[i] * 4);
    }
    for (int i = 0; i < 4; ++i) {
        gf[i] = (float*)alloc((size_t)NDIM[i] * 4);
        bef[i] = (float*)alloc((size_t)NDIM[i] * 4);
    }
    float* stats = (float*)alloc(1408 * 4);
    float* scale = (float*)alloc(256 * 4);
    float* shift = (float*)alloc(256 * 4);
    float *s1 = stats, *s2 = stats + 128, *s3 = stats + 384, *s4 = stats + 896;
    // big slots
    bf16* aggb = (bf16*)alloc((size_t)NN * 256 * 2);  // also holds xb during layer 1
    bf16* S1 = (bf16*)alloc((size_t)NN * 256 * 2);
    bf16* S2 = (bf16*)alloc((size_t)NN * 256 * 2);
    bf16* xb = aggb;                         // NN*196 bf16 = 39.2 MB, fits in aggb slot
    bf16* u1 = S2;                           // NN*64 bf16, layer-1 scratch in S2

    if (off > ws_size) {
        // diagnostic: unmistakable constant output => "workspace too small"
        long long n = (long long)NN * 576;
        fill_kernel<<<(int)((n + 255) / 256), 256, 0, stream>>>((bf16*)d_out, n);
        return;
    }

    hipMemsetAsync(cnt, 0, (size_t)NN * 4, stream);
    hipMemsetAsync(stats, 0, 1408 * 4, stream);

    detect_kernel<<<1, 64, 0, stream>>>((const unsigned int*)x_raw, flags);

    // canonicalize inputs to bf16 / fp32
    {
        int n4 = NN * 196 / 4;
        cvt_bf16_kernel<<<(n4 + 255) / 256, 256, 0, stream>>>(x_raw, xb, n4, flags);
        for (int i = 0; i < 5; ++i) {
            int nw4 = KDIM[i] * NDIM[i] / 4;
            cvt_bf16_kernel<<<(nw4 + 255) / 256, 256, 0, stream>>>(d_in[2 + 3 * i], Wlb[i], nw4, flags);
            cvt_bf16_kernel<<<(nw4 + 255) / 256, 256, 0, stream>>>(d_in[3 + 3 * i], Wrb[i], nw4, flags);
            cvt_f32_kernel<<<(NDIM[i] + 255) / 256, 256, 0, stream>>>(d_in[4 + 3 * i], bf_[i], NDIM[i], flags);
        }
        for (int i = 0; i < 4; ++i) {
            cvt_f32_kernel<<<(NDIM[i] + 255) / 256, 256, 0, stream>>>(d_in[17 + 2 * i], gf[i], NDIM[i], flags);
            cvt_f32_kernel<<<(NDIM[i] + 255) / 256, 256, 0, stream>>>(d_in[18 + 2 * i], bef[i], NDIM[i], flags);
        }
    }

    count_kernel<<<(NE + 255) / 256, 256, 0, stream>>>(dst, cnt);
    scan_kernel<<<1, 1024, 0, stream>>>(cnt, indptr, cursor, recip);
    scatter_kernel<<<(NE + 255) / 256, 256, 0, stream>>>(src, dst, cursor, csr);

    const int GM = (NN + 63) / 64;  // 1563

    // ---- Layer 1: 196 -> 64 (aggregate AFTER lin_l: gather 64 dims, not 196)
    gemm_kernel<<<dim3(GM, 1), 256, 0, stream>>>(xb, Wlb[0], 196, nullptr, nullptr, 0,
                                                 nullptr, u1, nullptr, flags, NN, 64);
    gemm_kernel<<<dim3(GM, 1), 256, 0, stream>>>(xb, Wrb[0], 196, nullptr, nullptr, 0,
                                                 bf_[0], S1, nullptr, flags, NN, 64);
    agg_kernel<1><<<NN / 4, 256, 0, stream>>>(u1, indptr, csr, recip, 6, S1);
    bn_stats_kernel<<<GM, 256, 0, stream>>>(S1, 6, s1);
    bn_finalize_kernel<<<1, 256, 0, stream>>>(s1, gf[0], bef[0], 64, scale, shift);
    bn_apply_kernel<<<(NN * 64 + 255) / 256, 256, 0, stream>>>(S1, scale, shift, 63, S1,
                                                               (long long)NN * 64);

    // ---- Layer 2: 64 -> 128  (act1 in S1)
    agg_kernel<0><<<NN / 4, 256, 0, stream>>>(S1, indptr, csr, recip, 6, aggb);
    gemm_kernel<<<dim3(GM, 2), 256, 0, stream>>>(aggb, Wlb[1], 64, S1, Wrb[1], 64,
                                                 bf_[1], S2, nullptr, flags, NN, 128);
    bn_stats_kernel<<<GM, 256, 0, stream>>>(S2, 7, s2);
    bn_finalize_kernel<<<1, 256, 0, stream>>>(s2, gf[1], bef[1], 128, scale, shift);
    bn_apply_kernel<<<(NN * 128 + 255) / 256, 256, 0, stream>>>(S2, scale, shift, 127, S2,
                                                                (long long)NN * 128);

    // ---- Layer 3: 128 -> 256  (act2 in S2)
    agg_kernel<0><<<NN / 2, 256, 0, stream>>>(S2, indptr, csr, recip, 7, aggb);
    gemm_kernel<<<dim3(GM, 4), 256, 0, stream>>>(aggb, Wlb[2], 128, S2, Wrb[2], 128,
                                                 bf_[2], S1, nullptr, flags, NN, 256);
    bn_stats_kernel<<<GM, 256, 0, stream>>>(S1, 8, s3);
    bn_finalize_kernel<<<1, 256, 0, stream>>>(s3, gf[2], bef[2], 256, scale, shift);
    bn_apply_kernel<<<(NN * 256 + 255) / 256, 256, 0, stream>>>(S1, scale, shift, 255, S1,
                                                                (long long)NN * 256);

    // ---- Layer 4: 256 -> 256  (act3 in S1)
    agg_kernel<0><<<NN, 256, 0, stream>>>(S1, indptr, csr, recip, 8, aggb);
    gemm_kernel<<<dim3(GM, 4), 256, 0, stream>>>(aggb, Wlb[3], 256, S1, Wrb[3], 256,
                                                 bf_[3], S2, nullptr, flags, NN, 256);
    bn_stats_kernel<<<GM, 256, 0, stream>>>(S2, 8, s4);
    bn_finalize_kernel<<<1, 256, 0, stream>>>(s4, gf[3], bef[3], 256, scale, shift);
    bn_apply_kernel<<<(NN * 256 + 255) / 256, 256, 0, stream>>>(S2, scale, shift, 255, S2,
                                                                (long long)NN * 256);

    // ---- Layer 5: 256 -> 576, no BN/ReLU, write d_out (bf16 or fp32 per flag)
    agg_kernel<0><<<NN, 256, 0, stream>>>(S2, indptr, csr, recip, 8, aggb);
    gemm_kernel<<<dim3(GM, 9), 256, 0, stream>>>(aggb, Wlb[4], 256, S2, Wrb[4], 256,
                                                 bf_[4], nullptr, d_out, flags, NN, 576);
}